// Round 9
// baseline (1520.828 us; speedup 1.0000x reference)
//
#include <hip/hip_runtime.h>
#include <math.h>

#define NB 4096
#define NH 3
#define NK 32768
#define ND 128
#define KA 256           // A stored K: [rh(128) | rl(128)]
#define KB 256           // B stored K: [wh(128) | wl(128)]  (dedup: wh read twice via regs)
#define RB 128           // rows per block
#define CS 16            // column splits (2 per XCD)
#define CPB (NK / CS)    // 2048 cols per block
#define CI 128           // cols per col-iteration (4 col-groups x 32)
#define NCI (CPB / CI)   // 16 col-iterations per block (ci fits a nibble)

typedef _Float16 half8_t __attribute__((ext_vector_type(8)));
typedef _Float16 half2_t __attribute__((ext_vector_type(2)));
typedef float f32x4 __attribute__((ext_vector_type(4)));
typedef float f32x16 __attribute__((ext_vector_type(16)));
typedef __attribute__((address_space(1))) const unsigned int gu32_t;
typedef __attribute__((address_space(3))) unsigned int lu32_t;

#define MFMA32(A_, B_, C_) __builtin_amdgcn_mfma_f32_32x32x16_f16((A_), (B_), (C_), 0, 0, 0)

// ---------------------------------------------------------------------------
// init: resid = inputs, quantized = 0, loss = 0, rr = sum(resid^2), Aext row.
__global__ __launch_bounds__(64) void init_kernel(const float* __restrict__ inp,
                                                  float* __restrict__ resid,
                                                  float* __restrict__ rr,
                                                  float* __restrict__ out,
                                                  _Float16* __restrict__ Aext) {
  int row = blockIdx.x;
  int lane = threadIdx.x;
  const float2* ip = (const float2*)(inp + row * ND);
  float2 v = ip[lane];
  ((float2*)(resid + row * ND))[lane] = v;
  ((float2*)(out + NB + row * ND))[lane] = make_float2(0.f, 0.f);
  if (lane == 0) out[row] = 0.f; // loss
  _Float16 h0 = (_Float16)v.x, h1 = (_Float16)v.y;
  _Float16 l0 = (_Float16)(v.x - (float)h0), l1 = (_Float16)(v.y - (float)h1);
  half2_t h = {h0, h1}, l = {l0, l1};
  _Float16* base = Aext + (size_t)row * KA;
  *(half2_t*)(base + 2 * lane) = h;       // rh
  *(half2_t*)(base + 128 + 2 * lane) = l; // rl
  float s = v.x * v.x + v.y * v.y;
  #pragma unroll
  for (int m = 32; m; m >>= 1) s += __shfl_xor(s, m, 64);
  if (lane == 0) rr[row] = s;
}

// ---------------------------------------------------------------------------
// norms[row] = sum(W[row]^2) for all H*K rows (one wave per row), fp32 exact.
// NOTE: do NOT change this reduction tree — its rounding order is what the
// reference-matching argmax ties were validated against.
__global__ __launch_bounds__(256) void norms_kernel(const float* __restrict__ emb,
                                                    float* __restrict__ norms) {
  int row = blockIdx.x * 4 + (threadIdx.x >> 6);
  int lane = threadIdx.x & 63;
  const float2* wp = (const float2*)(emb + (size_t)row * ND);
  float2 v = wp[lane];
  float s = v.x * v.x + v.y * v.y;
  #pragma unroll
  for (int m = 32; m; m >>= 1) s += __shfl_xor(s, m, 64);
  if (lane == 0) norms[row] = s;
}

// ---------------------------------------------------------------------------
// fp32 -> (hi,lo) fp16 split for the 32x32x16 fragment layout.
// Bext per head: [group:1024 (32 cols)][ks:16][lane:64][8 f16]
//   ks 0..7 = wh ksteps (k = ks*16..+16), ks 8..15 = wl.
//   fragment lane l: col = group*32 + (l&31), k = ks*16 + (l>>5)*8 + j.
__global__ __launch_bounds__(256) void split_w_all_kernel(const float* __restrict__ emb,
                                                          _Float16* __restrict__ Bext) {
  const int head = blockIdx.x >> 10;      // 0..2
  const int g = blockIdx.x & 1023;        // col32 group
  const int coll = threadIdx.x & 31;
  const int idx = threadIdx.x >> 5;       // 0..7
  const int n = g * 32 + coll;

  _Float16* gb = Bext + (size_t)head * NK * KB + (size_t)g * 8192;
  const float* src = emb + (size_t)head * NK * ND + (size_t)n * ND;

  #pragma unroll
  for (int iter = 0; iter < 2; ++iter) {
    const int kh = idx + iter * 8; // 0..15 half-kstep
    const int ks = kh >> 1, hi = kh & 1;
    const int k = ks * 16 + hi * 8;
    const float4* wp = (const float4*)(src + k);
    float4 v0 = wp[0], v1 = wp[1];
    float xv[8] = {v0.x, v0.y, v0.z, v0.w, v1.x, v1.y, v1.z, v1.w};
    half8_t h, l;
    #pragma unroll
    for (int j = 0; j < 8; ++j) {
      _Float16 hh = (_Float16)xv[j];
      h[j] = hh;
      l[j] = (_Float16)(xv[j] - (float)hh);
    }
    const int lanef = hi * 32 + coll;
    *(half8_t*)(gb + ks * 512 + lanef * 8) = h;       // wh
    *(half8_t*)(gb + (8 + ks) * 512 + lanef * 8) = l; // wl
  }
}

// ---------------------------------------------------------------------------
// Barrier-free score kernel — R9: 32x32x16 MFMA shape. Rationale: R8 measured
// MfmaUtil 49% with the 16x16x32 floor at 48 of 97.7us and weak TLP
// sensitivity (2->4 waves/SIMD = +5%); shape switch cuts the floor 17%
// (2495 vs 2075 TF rate) AND halves MFMA instruction issue (96->48/wave-ci).
// 512-thread block, 8 waves of 64r x 32c (wr=wn>>2, wc=wn&3), two stacked
// 32x32 acc tiles. Per kstep(16k): 2 B loads + 4 A ds_reads + 6 MFMAs
// (wh feeds rh+rl passes, wl feeds rh).
// A LDS layout [m:128][slot:32][8f16], slot = chunk ^ (m&31): 32-lane reads
// hit 32 distinct 16B slots -> bank-conflict-free (watch SQ_LDS_BANK_CONFLICT
// drop vs R8's 37.5k as the mechanism check).
// Fragment maps (HW-verified guide tables): A/B lane l: row|col = l&31,
// k = (l>>5)*8+j; C: col = l&31, row = (reg&3)+8*(reg>>2)+4*(l>>5).
// Each lane owns ONE column -> 1 normh load/ci; 32 rows/lane -> index
// tracked as PACKED NIBBLES (ci in [0,16)): pk[4] VGPRs, keeps the budget
// at ~120 <= 128 for 4 waves/SIMD (R2/R4 lesson: spills are fatal).
// Tie-break: per slot one cidx per ci, strictly decreasing; ">=" keeps
// lowest index; cross-lane/block comparator (>, ==&&<) handles col ties.
// bid&15 = col-split; 2 x 1 MB B slices per XCD's L2 (cs mod 8 == xcd).
__global__ __launch_bounds__(512, 4) void score_mfma_kernel(
    const _Float16* __restrict__ Aext, const _Float16* __restrict__ Bext,
    const float* __restrict__ rr, const float* __restrict__ normh,
    float* __restrict__ partial_s, int* __restrict__ partial_i) {
  __shared__ __align__(16) _Float16 Ash[RB * KA]; // 64 KB: [m:128][slot:32][8 f16]
  __shared__ __align__(16) float rrsh[RB];        // 512 B

  const int bid = blockIdx.x;
  const int cs = bid & (CS - 1);
  const int rowb = bid >> 4;
  const int rowBase = rowb * RB;
  const int colBase0 = cs * CPB;

  const int tid = threadIdx.x;
  const int lane = tid & 63;
  const int wn = tid >> 6; // wave 0..7
  const int wc = wn & 3;   // col-group (32 cols)
  const int wr = wn >> 2;  // row-half (64 rows)
  const int cl = lane & 31;
  const int hi = lane >> 5;

  // ---- stage A panel (once): wave wn stages rows wn*16..+16 (8 KB) ----
  // LDS[m][slot] = A[rowBase+m][chunk = slot ^ (m&31)]  (chunk = 8 f16)
  {
    #pragma unroll
    for (int i = 0; i < 8; ++i) {
      const int m0 = wn * 16 + i * 2;
      const int ml = m0 + hi;
      const int c = cl ^ (ml & 31);
      const _Float16* gA = Aext + (size_t)(rowBase + ml) * KA + c * 8;
      __builtin_amdgcn_global_load_lds((gu32_t*)gA, (lu32_t*)&Ash[m0 * 256], 16, 0, 0);
    }
  }
  if (tid < RB) rrsh[tid] = rr[rowBase + tid];

  // per-lane A byte addresses (even parity); read addr = Q[t]^(ks*32)^(src*256)
  // addr = m*512 + (chunk ^ (m&31))*16, chunk = ks*2 + hi + src*16 (disjoint bits)
  int Q[2];
  #pragma unroll
  for (int t = 0; t < 2; ++t) {
    const int ml = wr * 64 + t * 32 + cl;
    Q[t] = (ml * 512 + (ml & 31) * 16) ^ (hi * 16);
  }

  float bs[32];
  int pk[4];
  #pragma unroll
  for (int t = 0; t < 32; ++t) bs[t] = -INFINITY;
  #pragma unroll
  for (int t = 0; t < 4; ++t) pk[t] = 0;

  __syncthreads(); // the only barrier before the epilogue

  const f32x16 Z = {0.f, 0.f, 0.f, 0.f, 0.f, 0.f, 0.f, 0.f,
                    0.f, 0.f, 0.f, 0.f, 0.f, 0.f, 0.f, 0.f};
  const char* AshB = (const char*)Ash;

  #pragma unroll 1
  for (int ci = NCI - 1; ci >= 0; --ci) {
    const int ncol = colBase0 + ci * CI + wc * 32;
    const char* bp = (const char*)Bext +
                     ((unsigned)(ncol >> 5) * 16384u + (unsigned)lane * 16u);
    const float nw = normh[ncol + cl]; // issued early, used in fold

    f32x16 acc0, acc1;
    // ---- ks = 0, peeled: first MFMA pair consumes Z (no acc init) ----
    {
      half8_t bh = *(const half8_t*)(bp);
      half8_t bl = *(const half8_t*)(bp + 8 * 1024);
      half8_t a0h = *(const half8_t*)(AshB + Q[0]);
      half8_t a1h = *(const half8_t*)(AshB + Q[1]);
      half8_t a0l = *(const half8_t*)(AshB + (Q[0] ^ 256));
      half8_t a1l = *(const half8_t*)(AshB + (Q[1] ^ 256));
      __builtin_amdgcn_s_setprio(1);
      acc0 = MFMA32(a0h, bh, Z);
      acc1 = MFMA32(a1h, bh, Z);
      acc0 = MFMA32(a0l, bh, acc0);
      acc1 = MFMA32(a1l, bh, acc1);
      acc0 = MFMA32(a0h, bl, acc0);
      acc1 = MFMA32(a1h, bl, acc1);
      __builtin_amdgcn_s_setprio(0);
    }
    // ---- ks = 1..7 ----
    #pragma unroll 2
    for (int ks = 1; ks < 8; ++ks) {
      half8_t bh = *(const half8_t*)(bp + ks * 1024);
      half8_t bl = *(const half8_t*)(bp + (8 + ks) * 1024);
      half8_t a0h = *(const half8_t*)(AshB + (Q[0] ^ (ks * 32)));
      half8_t a1h = *(const half8_t*)(AshB + (Q[1] ^ (ks * 32)));
      half8_t a0l = *(const half8_t*)(AshB + (Q[0] ^ (ks * 32) ^ 256));
      half8_t a1l = *(const half8_t*)(AshB + (Q[1] ^ (ks * 32) ^ 256));
      __builtin_amdgcn_s_setprio(1);
      acc0 = MFMA32(a0h, bh, acc0);
      acc1 = MFMA32(a1h, bh, acc1);
      acc0 = MFMA32(a0l, bh, acc0);
      acc1 = MFMA32(a1l, bh, acc1);
      acc0 = MFMA32(a0h, bl, acc0);
      acc1 = MFMA32(a1h, bl, acc1);
      __builtin_amdgcn_s_setprio(0);
    }

    // ---- fold into running argmax (index as packed nibble = ci) ----
    // Each lane-slot sees ONE col (cidx strictly decreasing across ci),
    // so ">=" keeps the lowest index, matching jnp.argmax.
    int vci[8];
    #pragma unroll
    for (int j = 0; j < 8; ++j) vci[j] = ci << (4 * j);
#define FOLD_TILE(T_, ACC_)                                                    \
    _Pragma("unroll")                                                          \
    for (int g = 0; g < 4; ++g) {                                              \
      const f32x4 r4 = *(const f32x4*)&rrsh[wr * 64 + (T_)*32 + hi * 4 + g * 8]; \
      _Pragma("unroll")                                                        \
      for (int j = 0; j < 4; ++j) {                                            \
        const int r = g * 4 + j;                                               \
        const int s = (T_)*16 + r;                                             \
        float t1 = r4[j] + nw;                    /* fl(rr + |w|^2), as ref */ \
        float v = fmaf(2.0f, (ACC_)[r], -t1);     /* == fl(2*acc - t1)     */  \
        bool u = (v >= bs[s]);                                                 \
        bs[s] = u ? v : bs[s];                                                 \
        int upd = (pk[s >> 3] & ~(0xF << ((s & 7) * 4))) | vci[s & 7];         \
        pk[s >> 3] = u ? upd : pk[s >> 3];                                     \
      }                                                                        \
    }
    FOLD_TILE(0, acc0)
    FOLD_TILE(1, acc1)
#undef FOLD_TILE
  }

  // ---- block argmax reduction (overlay scratch on Ash) ----
  __syncthreads(); // all LDS A-reads complete
  float* red_s = (float*)Ash;      // [128][4]
  int* red_i = (int*)Ash + RB * 4; // [128][4]
  const int cbase = colBase0 + wc * 32 + cl;
  #pragma unroll
  for (int s = 0; s < 32; ++s) {
    float v = bs[s];
    int ciS = (pk[s >> 3] >> ((s & 7) * 4)) & 15;
    int ii = cbase + ciS * CI;
    // reduce over the 32 cols (lanes within each 32-half hold the same rows)
    #pragma unroll
    for (int mask = 1; mask <= 16; mask <<= 1) {
      float os = __shfl_xor(v, mask, 64);
      int oi = __shfl_xor(ii, mask, 64);
      if (os > v || (os == v && oi < ii)) { v = os; ii = oi; }
    }
    if (cl == 0) {
      const int t = s >> 4, r = s & 15;
      const int row = wr * 64 + t * 32 + (r & 3) + 8 * (r >> 2) + 4 * hi;
      red_s[row * 4 + wc] = v;
      red_i[row * 4 + wc] = ii;
    }
  }
  __syncthreads();
  if (tid < RB) {
    float s0 = red_s[tid * 4];
    int i0 = red_i[tid * 4];
    #pragma unroll
    for (int x = 1; x < 4; ++x) {
      float sx = red_s[tid * 4 + x];
      int ix = red_i[tid * 4 + x];
      if (sx > s0 || (sx == s0 && ix < i0)) { s0 = sx; i0 = ix; }
    }
    partial_s[(size_t)(rowBase + tid) * CS + cs] = s0;
    partial_i[(size_t)(rowBase + tid) * CS + cs] = i0;
  }
}

// ---------------------------------------------------------------------------
// Combine col-split partials -> code; resid -= W[c]; quantized += W[c];
// new rr; Aext row for next head.
__global__ __launch_bounds__(64) void reduce_update_kernel(const float* __restrict__ embh,
                                                           float* __restrict__ resid,
                                                           float* __restrict__ rr,
                                                           const float* __restrict__ ps,
                                                           const int* __restrict__ pi,
                                                           float* __restrict__ out,
                                                           _Float16* __restrict__ Aext, int h) {
  int row = blockIdx.x;
  int lane = threadIdx.x;
  float bs = -INFINITY;
  int bi = 0x7fffffff;
  if (lane < CS) {
    bs = ps[(size_t)row * CS + lane];
    bi = pi[(size_t)row * CS + lane];
  }
  #pragma unroll
  for (int m = 8; m; m >>= 1) {
    float os = __shfl_xor(bs, m, 64);
    int oi = __shfl_xor(bi, m, 64);
    if (os > bs || (os == bs && oi < bi)) { bs = os; bi = oi; }
  }
  int c = __shfl(bi, 0, 64);
  if (lane == 0) out[NB + NB * ND + row * NH + h] = (float)c; // codes as f32

  const float* wv = embh + (size_t)c * ND;
  float q0 = wv[lane], q1 = wv[lane + 64];
  float r0 = resid[row * ND + lane] - q0;
  float r1 = resid[row * ND + lane + 64] - q1;
  resid[row * ND + lane] = r0;
  resid[row * ND + lane + 64] = r1;
  out[NB + row * ND + lane] += q0;
  out[NB + row * ND + lane + 64] += q1;

  // Aext row for the next head (harmless extra work on the last head)
  _Float16 h0 = (_Float16)r0, l0 = (_Float16)(r0 - (float)h0);
  _Float16 h1 = (_Float16)r1, l1 = (_Float16)(r1 - (float)h1);
  _Float16* ab = Aext + (size_t)row * KA;
  ab[lane] = h0;       ab[lane + 64] = h1;       // rh
  ab[128 + lane] = l0; ab[128 + lane + 64] = l1; // rl

  float s = r0 * r0 + r1 * r1;
  #pragma unroll
  for (int m = 32; m; m >>= 1) s += __shfl_xor(s, m, 64);
  if (lane == 0) rr[row] = s;
}

// ---------------------------------------------------------------------------
extern "C" void kernel_launch(void* const* d_in, const int* in_sizes, int n_in,
                              void* d_out, int out_size, void* d_ws, size_t ws_size,
                              hipStream_t stream) {
  const float* inp = (const float*)d_in[0]; // (4096,1,128)
  const float* emb = (const float*)d_in[1]; // (3,32768,128)
  float* out = (float*)d_out;               // loss | quantized | codes

  float* resid = (float*)d_ws;                        // NB*ND f32
  float* rr = resid + NB * ND;                        // NB
  float* norms = rr + NB;                             // NH*NK
  float* ps = norms + NH * NK;                        // NB*CS f32
  int* pi = (int*)(ps + (size_t)NB * CS);             // NB*CS i32
  _Float16* Aext = (_Float16*)(pi + (size_t)NB * CS); // NB*KA f16
  _Float16* Bext = Aext + (size_t)NB * KA;            // NH*NK*KB f16 (~50 MB)

  hipLaunchKernelGGL(init_kernel, dim3(NB), dim3(64), 0, stream, inp, resid, rr, out, Aext);
  hipLaunchKernelGGL(norms_kernel, dim3(NH * NK / 4), dim3(256), 0, stream, emb, norms);
  hipLaunchKernelGGL(split_w_all_kernel, dim3(NH * NK / 32), dim3(256), 0, stream, emb, Bext);
  for (int h = 0; h < NH; ++h) {
    hipLaunchKernelGGL(score_mfma_kernel, dim3((NB / RB) * CS), dim3(512), 0, stream,
                       Aext, Bext + (size_t)h * NK * KB, rr, norms + (size_t)h * NK, ps, pi);
    hipLaunchKernelGGL(reduce_update_kernel, dim3(NB), dim3(64), 0, stream,
                       emb + (size_t)h * NK * ND, resid, rr, ps, pi, out, Aext, h);
  }
}

// Round 10
// 500.493 us; speedup vs baseline: 3.0387x; 3.0387x over previous
//
#include <hip/hip_runtime.h>
#include <math.h>

#define NB 4096
#define NH 3
#define NK 32768
#define ND 128
#define KA 256           // A stored K: [rh(128) | rl(128)]
#define KB 256           // B stored K: [wh(128) | wl(128)]  (dedup: wh read twice via regs)
#define RB 128           // rows per block
#define CS 16            // column splits (2 per XCD)
#define CPB (NK / CS)    // 2048 cols per block
#define CI 64            // cols per col-iteration (2 col-groups x 32)
#define NCI (CPB / CI)   // 32 col-iterations per block (ci fits a byte)

typedef _Float16 half8_t __attribute__((ext_vector_type(8)));
typedef _Float16 half2_t __attribute__((ext_vector_type(2)));
typedef float f32x4 __attribute__((ext_vector_type(4)));
typedef float f32x16 __attribute__((ext_vector_type(16)));
typedef __attribute__((address_space(1))) const unsigned int gu32_t;
typedef __attribute__((address_space(3))) unsigned int lu32_t;

#define MFMA32(A_, B_, C_) __builtin_amdgcn_mfma_f32_32x32x16_f16((A_), (B_), (C_), 0, 0, 0)

// ---------------------------------------------------------------------------
// init: resid = inputs, quantized = 0, loss = 0, rr = sum(resid^2), Aext row.
__global__ __launch_bounds__(64) void init_kernel(const float* __restrict__ inp,
                                                  float* __restrict__ resid,
                                                  float* __restrict__ rr,
                                                  float* __restrict__ out,
                                                  _Float16* __restrict__ Aext) {
  int row = blockIdx.x;
  int lane = threadIdx.x;
  const float2* ip = (const float2*)(inp + row * ND);
  float2 v = ip[lane];
  ((float2*)(resid + row * ND))[lane] = v;
  ((float2*)(out + NB + row * ND))[lane] = make_float2(0.f, 0.f);
  if (lane == 0) out[row] = 0.f; // loss
  _Float16 h0 = (_Float16)v.x, h1 = (_Float16)v.y;
  _Float16 l0 = (_Float16)(v.x - (float)h0), l1 = (_Float16)(v.y - (float)h1);
  half2_t h = {h0, h1}, l = {l0, l1};
  _Float16* base = Aext + (size_t)row * KA;
  *(half2_t*)(base + 2 * lane) = h;       // rh
  *(half2_t*)(base + 128 + 2 * lane) = l; // rl
  float s = v.x * v.x + v.y * v.y;
  #pragma unroll
  for (int m = 32; m; m >>= 1) s += __shfl_xor(s, m, 64);
  if (lane == 0) rr[row] = s;
}

// ---------------------------------------------------------------------------
// norms[row] = sum(W[row]^2) for all H*K rows (one wave per row), fp32 exact.
// NOTE: do NOT change this reduction tree — its rounding order is what the
// reference-matching argmax ties were validated against.
__global__ __launch_bounds__(256) void norms_kernel(const float* __restrict__ emb,
                                                    float* __restrict__ norms) {
  int row = blockIdx.x * 4 + (threadIdx.x >> 6);
  int lane = threadIdx.x & 63;
  const float2* wp = (const float2*)(emb + (size_t)row * ND);
  float2 v = wp[lane];
  float s = v.x * v.x + v.y * v.y;
  #pragma unroll
  for (int m = 32; m; m >>= 1) s += __shfl_xor(s, m, 64);
  if (lane == 0) norms[row] = s;
}

// ---------------------------------------------------------------------------
// fp32 -> (hi,lo) fp16 split for the 32x32x16 fragment layout (R9-verified).
// Bext per head: [group:1024 (32 cols)][ks:16][lane:64][8 f16]
//   ks 0..7 = wh ksteps (k = ks*16..+16), ks 8..15 = wl.
//   fragment lane l: col = group*32 + (l&31), k = ks*16 + (l>>5)*8 + j.
__global__ __launch_bounds__(256) void split_w_all_kernel(const float* __restrict__ emb,
                                                          _Float16* __restrict__ Bext) {
  const int head = blockIdx.x >> 10;      // 0..2
  const int g = blockIdx.x & 1023;        // col32 group
  const int coll = threadIdx.x & 31;
  const int idx = threadIdx.x >> 5;       // 0..7
  const int n = g * 32 + coll;

  _Float16* gb = Bext + (size_t)head * NK * KB + (size_t)g * 8192;
  const float* src = emb + (size_t)head * NK * ND + (size_t)n * ND;

  #pragma unroll
  for (int iter = 0; iter < 2; ++iter) {
    const int kh = idx + iter * 8; // 0..15 half-kstep
    const int ks = kh >> 1, hi = kh & 1;
    const int k = ks * 16 + hi * 8;
    const float4* wp = (const float4*)(src + k);
    float4 v0 = wp[0], v1 = wp[1];
    float xv[8] = {v0.x, v0.y, v0.z, v0.w, v1.x, v1.y, v1.z, v1.w};
    half8_t h, l;
    #pragma unroll
    for (int j = 0; j < 8; ++j) {
      _Float16 hh = (_Float16)xv[j];
      h[j] = hh;
      l[j] = (_Float16)(xv[j] - (float)hh);
    }
    const int lanef = hi * 32 + coll;
    *(half8_t*)(gb + ks * 512 + lanef * 8) = h;       // wh
    *(half8_t*)(gb + (8 + ks) * 512 + lanef * 8) = l; // wl
  }
}

// ---------------------------------------------------------------------------
// Barrier-free score kernel — R10: 32x32x16 shape (fragment algebra verified
// correct in R9; R9 spilled: bs[32]+vci[8]+unroll-2 transients > 128 regs,
// 324 MB scratch writes). Fix: ONE 32x32 tile per wave — 8 waves = 4 row-
// quarters x 2 col-groups (wq=wn>>1, wc=wn&1), CI=64, NCI=32. Persistent
// state: bs[16] + BYTE-packed indices pkb[4] (ci<256) + Q ~= 21 regs; acc =
// one f32x16; ks loop unroll 1, frag transients 16 -> total ~60-80 regs,
// real headroom under the 128 cap of __launch_bounds__(512,4) = 4 waves/SIMD,
// grid 512 = 2 blocks/CU tail-free. (R2/R4/R9 lesson encoded: never let
// persistent-state + transients approach the cap.)
// A LDS [m:128][slot:32][8f16], slot = chunk ^ (m&31): conflict-free 32-lane
// reads. B traffic per block unchanged (same col-slice); intra-col-group
// B re-reads by 4 waves are L1 hits.
// Fragment maps (R9-verified): A/B lane l: row|col = l&31, k = (l>>5)*8+j;
// C: col = l&31, row = (reg&3)+8*(reg>>2)+4*(l>>5).
// Tie-break: each lane-slot sees ONE col per ci, ci descending => cidx
// strictly decreasing, ">=" keeps lowest index; cross-lane/block comparator
// (>, ==&&<) handles col ties. Matches jnp.argmax.
// bid&15 = col-split; 2 x 1 MB B slices per XCD's L2 (cs mod 8 == xcd).
__global__ __launch_bounds__(512, 4) void score_mfma_kernel(
    const _Float16* __restrict__ Aext, const _Float16* __restrict__ Bext,
    const float* __restrict__ rr, const float* __restrict__ normh,
    float* __restrict__ partial_s, int* __restrict__ partial_i) {
  __shared__ __align__(16) _Float16 Ash[RB * KA]; // 64 KB: [m:128][slot:32][8 f16]
  __shared__ __align__(16) float rrsh[RB];        // 512 B

  const int bid = blockIdx.x;
  const int cs = bid & (CS - 1);
  const int rowb = bid >> 4;
  const int rowBase = rowb * RB;
  const int colBase0 = cs * CPB;

  const int tid = threadIdx.x;
  const int lane = tid & 63;
  const int wn = tid >> 6; // wave 0..7
  const int wc = wn & 1;   // col-group (32 cols)
  const int wq = wn >> 1;  // row-quarter (32 rows)
  const int cl = lane & 31;
  const int hi = lane >> 5;

  // ---- stage A panel (once): wave wn stages rows wn*16..+16 (8 KB) ----
  // LDS[m][slot] = A[rowBase+m][chunk = slot ^ (m&31)]  (chunk = 8 f16)
  // (identical to R9 — verified)
  {
    #pragma unroll
    for (int i = 0; i < 8; ++i) {
      const int m0 = wn * 16 + i * 2;
      const int ml = m0 + hi;
      const int c = cl ^ (ml & 31);
      const _Float16* gA = Aext + (size_t)(rowBase + ml) * KA + c * 8;
      __builtin_amdgcn_global_load_lds((gu32_t*)gA, (lu32_t*)&Ash[m0 * 256], 16, 0, 0);
    }
  }
  if (tid < RB) rrsh[tid] = rr[rowBase + tid];

  // per-lane A byte address (even parity); read addr = Q ^ (ks*32) ^ (src*256)
  // addr = m*512 + (chunk ^ (m&31))*16, chunk = ks*2 + hi + src*16
  int Q;
  {
    const int ml = wq * 32 + cl;
    Q = (ml * 512 + (ml & 31) * 16) ^ (hi * 16);
  }

  float bs[16];
  int pkb[4];
  #pragma unroll
  for (int t = 0; t < 16; ++t) bs[t] = -INFINITY;
  #pragma unroll
  for (int t = 0; t < 4; ++t) pkb[t] = 0;

  __syncthreads(); // the only barrier before the epilogue

  const f32x16 Z = {0.f, 0.f, 0.f, 0.f, 0.f, 0.f, 0.f, 0.f,
                    0.f, 0.f, 0.f, 0.f, 0.f, 0.f, 0.f, 0.f};
  const char* AshB = (const char*)Ash;

  #pragma unroll 1
  for (int ci = NCI - 1; ci >= 0; --ci) {
    const int ncol = colBase0 + ci * CI + wc * 32;
    const char* bp = (const char*)Bext +
                     ((unsigned)(ncol >> 5) * 16384u + (unsigned)lane * 16u);
    const float nw = normh[ncol + cl]; // issued early, used in fold

    f32x16 acc;
    // ---- ks = 0, peeled: first MFMA consumes Z (no acc init) ----
    {
      half8_t bh = *(const half8_t*)(bp);
      half8_t bl = *(const half8_t*)(bp + 8 * 1024);
      half8_t ah = *(const half8_t*)(AshB + Q);
      half8_t al = *(const half8_t*)(AshB + (Q ^ 256));
      __builtin_amdgcn_s_setprio(1);
      acc = MFMA32(ah, bh, Z);
      acc = MFMA32(al, bh, acc);
      acc = MFMA32(ah, bl, acc);
      __builtin_amdgcn_s_setprio(0);
    }
    // ---- ks = 1..7 ----
    #pragma unroll 1
    for (int ks = 1; ks < 8; ++ks) {
      half8_t bh = *(const half8_t*)(bp + ks * 1024);
      half8_t bl = *(const half8_t*)(bp + (8 + ks) * 1024);
      half8_t ah = *(const half8_t*)(AshB + (Q ^ (ks * 32)));
      half8_t al = *(const half8_t*)(AshB + (Q ^ (ks * 32) ^ 256));
      __builtin_amdgcn_s_setprio(1);
      acc = MFMA32(ah, bh, acc);
      acc = MFMA32(al, bh, acc);
      acc = MFMA32(ah, bl, acc);
      __builtin_amdgcn_s_setprio(0);
    }

    // ---- fold into running argmax (index = ci packed as a byte) ----
    // One col per lane-slot, cidx strictly decreasing across ci, so ">="
    // keeps the lowest index, matching jnp.argmax.
    #pragma unroll
    for (int g = 0; g < 4; ++g) {
      const f32x4 r4 = *(const f32x4*)&rrsh[wq * 32 + hi * 4 + g * 8];
      #pragma unroll
      for (int j = 0; j < 4; ++j) {
        const int s = g * 4 + j;
        float t1 = r4[j] + nw;              // fl(rr + |w|^2), as ref
        float v = fmaf(2.0f, acc[s], -t1);  // == fl(2*acc - t1)
        bool u = (v >= bs[s]);
        bs[s] = u ? v : bs[s];
        const int sh = (s & 3) * 8;
        int upd = (pkb[s >> 2] & ~(0xFF << sh)) | (ci << sh);
        pkb[s >> 2] = u ? upd : pkb[s >> 2];
      }
    }
  }

  // ---- block argmax reduction (overlay scratch on Ash) ----
  __syncthreads(); // all LDS A-reads complete
  float* red_s = (float*)Ash;      // [128][2]
  int* red_i = (int*)Ash + RB * 2; // [128][2]
  const int cbase = colBase0 + wc * 32 + cl;
  #pragma unroll
  for (int s = 0; s < 16; ++s) {
    float v = bs[s];
    int ciS = (pkb[s >> 2] >> ((s & 3) * 8)) & 0xFF;
    int ii = cbase + ciS * CI;
    // reduce over the 32 cols (each 32-lane half holds disjoint rows)
    #pragma unroll
    for (int mask = 1; mask <= 16; mask <<= 1) {
      float os = __shfl_xor(v, mask, 64);
      int oi = __shfl_xor(ii, mask, 64);
      if (os > v || (os == v && oi < ii)) { v = os; ii = oi; }
    }
    if (cl == 0) {
      const int row = wq * 32 + (s & 3) + 8 * (s >> 2) + 4 * hi;
      red_s[row * 2 + wc] = v;
      red_i[row * 2 + wc] = ii;
    }
  }
  __syncthreads();
  if (tid < RB) {
    float s0 = red_s[tid * 2];
    int i0 = red_i[tid * 2];
    float sx = red_s[tid * 2 + 1];
    int ix = red_i[tid * 2 + 1];
    if (sx > s0 || (sx == s0 && ix < i0)) { s0 = sx; i0 = ix; }
    partial_s[(size_t)(rowBase + tid) * CS + cs] = s0;
    partial_i[(size_t)(rowBase + tid) * CS + cs] = i0;
  }
}

// ---------------------------------------------------------------------------
// Combine col-split partials -> code; resid -= W[c]; quantized += W[c];
// new rr; Aext row for next head.
__global__ __launch_bounds__(64) void reduce_update_kernel(const float* __restrict__ embh,
                                                           float* __restrict__ resid,
                                                           float* __restrict__ rr,
                                                           const float* __restrict__ ps,
                                                           const int* __restrict__ pi,
                                                           float* __restrict__ out,
                                                           _Float16* __restrict__ Aext, int h) {
  int row = blockIdx.x;
  int lane = threadIdx.x;
  float bs = -INFINITY;
  int bi = 0x7fffffff;
  if (lane < CS) {
    bs = ps[(size_t)row * CS + lane];
    bi = pi[(size_t)row * CS + lane];
  }
  #pragma unroll
  for (int m = 8; m; m >>= 1) {
    float os = __shfl_xor(bs, m, 64);
    int oi = __shfl_xor(bi, m, 64);
    if (os > bs || (os == bs && oi < bi)) { bs = os; bi = oi; }
  }
  int c = __shfl(bi, 0, 64);
  if (lane == 0) out[NB + NB * ND + row * NH + h] = (float)c; // codes as f32

  const float* wv = embh + (size_t)c * ND;
  float q0 = wv[lane], q1 = wv[lane + 64];
  float r0 = resid[row * ND + lane] - q0;
  float r1 = resid[row * ND + lane + 64] - q1;
  resid[row * ND + lane] = r0;
  resid[row * ND + lane + 64] = r1;
  out[NB + row * ND + lane] += q0;
  out[NB + row * ND + lane + 64] += q1;

  // Aext row for the next head (harmless extra work on the last head)
  _Float16 h0 = (_Float16)r0, l0 = (_Float16)(r0 - (float)h0);
  _Float16 h1 = (_Float16)r1, l1 = (_Float16)(r1 - (float)h1);
  _Float16* ab = Aext + (size_t)row * KA;
  ab[lane] = h0;       ab[lane + 64] = h1;       // rh
  ab[128 + lane] = l0; ab[128 + lane + 64] = l1; // rl

  float s = r0 * r0 + r1 * r1;
  #pragma unroll
  for (int m = 32; m; m >>= 1) s += __shfl_xor(s, m, 64);
  if (lane == 0) rr[row] = s;
}

// ---------------------------------------------------------------------------
extern "C" void kernel_launch(void* const* d_in, const int* in_sizes, int n_in,
                              void* d_out, int out_size, void* d_ws, size_t ws_size,
                              hipStream_t stream) {
  const float* inp = (const float*)d_in[0]; // (4096,1,128)
  const float* emb = (const float*)d_in[1]; // (3,32768,128)
  float* out = (float*)d_out;               // loss | quantized | codes

  float* resid = (float*)d_ws;                        // NB*ND f32
  float* rr = resid + NB * ND;                        // NB
  float* norms = rr + NB;                             // NH*NK
  float* ps = norms + NH * NK;                        // NB*CS f32
  int* pi = (int*)(ps + (size_t)NB * CS);             // NB*CS i32
  _Float16* Aext = (_Float16*)(pi + (size_t)NB * CS); // NB*KA f16
  _Float16* Bext = Aext + (size_t)NB * KA;            // NH*NK*KB f16 (~50 MB)

  hipLaunchKernelGGL(init_kernel, dim3(NB), dim3(64), 0, stream, inp, resid, rr, out, Aext);
  hipLaunchKernelGGL(norms_kernel, dim3(NH * NK / 4), dim3(256), 0, stream, emb, norms);
  hipLaunchKernelGGL(split_w_all_kernel, dim3(NH * NK / 32), dim3(256), 0, stream, emb, Bext);
  for (int h = 0; h < NH; ++h) {
    hipLaunchKernelGGL(score_mfma_kernel, dim3((NB / RB) * CS), dim3(512), 0, stream,
                       Aext, Bext + (size_t)h * NK * KB, rr, norms + (size_t)h * NK, ps, pi);
    hipLaunchKernelGGL(reduce_update_kernel, dim3(NB), dim3(64), 0, stream,
                       emb + (size_t)h * NK * ND, resid, rr, ps, pi, out, Aext, h);
  }
}